// Round 1
// baseline (2320.738 us; speedup 1.0000x reference)
//
#include <hip/hip_runtime.h>

#define T_STEPS 1024
#define NZV 60          // valid z width
#define ZK 64           // padded K for GEMM1
#define H 128
#define NY 8
#define NU 4
#define ZSTR 72         // padded LDS stride (shorts) for z
#define HSTR 136        // padded LDS stride (shorts) for h1/h2

typedef __attribute__((ext_vector_type(8))) short bf16x8;
typedef __attribute__((ext_vector_type(4))) short bf16x4;
typedef __attribute__((ext_vector_type(4))) float f32x4;

union V8 { bf16x8 v8; bf16x4 v4[2]; };

__device__ __forceinline__ unsigned short f2bf(float x) {
    unsigned u = __float_as_uint(x);
    u += 0x7FFFu + ((u >> 16) & 1u);
    return (unsigned short)(u >> 16);
}

// tanh(x) = 1 - 2/(exp(2x)+1); exp2 saturates to inf/0 so no clamp needed.
__device__ __forceinline__ float tanh_fast(float x) {
    float e = __builtin_amdgcn_exp2f(x * 2.8853900817779268f);
    return fmaf(-2.0f, __builtin_amdgcn_rcpf(e + 1.0f), 1.0f);
}

__global__ __launch_bounds__(64, 1)
void cstr_scan_kernel(const float* __restrict__ u_g, const float* __restrict__ z0_g,
                      const float* __restrict__ W1, const float* __restrict__ b1,
                      const float* __restrict__ W2, const float* __restrict__ b2,
                      const float* __restrict__ W3, const float* __restrict__ b3,
                      float* __restrict__ out) {
    __shared__ unsigned short zbuf[2][16][ZSTR];
    __shared__ unsigned short h1s[16][HSTR];
    __shared__ unsigned short h2s[16][HSTR];

    const int lane  = threadIdx.x;       // 0..63
    const int b0    = blockIdx.x * 16;   // batch row base
    const int col   = lane & 15;         // MFMA col / A row
    const int kg    = lane >> 4;         // 0..3 (k-group)
    const int wrow0 = kg * 4;            // C-frag row base
    const int urow  = lane >> 2;         // u/z-shift row
    const int uc    = lane & 3;

    // ---- preload weight B-fragments into registers (one-time) ----
    bf16x8 w1f[2][8], w2f[4][8], w3f[4];
    float b1v[8], b2v[8], b3v;
#pragma unroll
    for (int nt = 0; nt < 8; ++nt) {
        b1v[nt] = b1[nt * 16 + col];
        b2v[nt] = b2[nt * 16 + col];
    }
    b3v = (col < NY) ? b3[col] : 0.f;

#pragma unroll
    for (int kc = 0; kc < 2; ++kc)
#pragma unroll
        for (int nt = 0; nt < 8; ++nt) {
            bf16x8 v;
#pragma unroll
            for (int j = 0; j < 8; ++j) {
                int k = kc * 32 + kg * 8 + j;
                float w = (k < NZV) ? W1[k * H + nt * 16 + col] : 0.f;
                v[j] = (short)f2bf(w);
            }
            w1f[kc][nt] = v;
        }
#pragma unroll
    for (int kc = 0; kc < 4; ++kc)
#pragma unroll
        for (int nt = 0; nt < 8; ++nt) {
            bf16x8 v;
#pragma unroll
            for (int j = 0; j < 8; ++j) {
                int k = kc * 32 + kg * 8 + j;
                v[j] = (short)f2bf(W2[k * H + nt * 16 + col]);
            }
            w2f[kc][nt] = v;
        }
#pragma unroll
    for (int kc = 0; kc < 4; ++kc) {
        bf16x8 v;
#pragma unroll
        for (int j = 0; j < 8; ++j) {
            int k = kc * 32 + kg * 8 + j;
            float w = (col < NY) ? W3[k * NY + col] : 0.f;
            v[j] = (short)f2bf(w);
        }
        w3f[kc] = v;
    }

    // ---- init z state (bf16) ----
    {
        unsigned short* zs = &zbuf[0][0][0];
        for (int i = lane; i < 2 * 16 * ZSTR; i += 64) zs[i] = 0;
        __syncthreads();
        for (int i = lane; i < 16 * NZV; i += 64) {
            int r = i / NZV, c = i - r * NZV;
            zbuf[0][r][c] = f2bf(z0_g[(size_t)(b0 + r) * NZV + c]);
        }
        __syncthreads();
    }

    int cur = 0;
#pragma unroll 1
    for (int t = 0; t < T_STEPS; ++t) {
        // prefetch u_t (consumed at z-update below)
        float ureg = u_g[(size_t)(b0 + urow) * (T_STEPS * NU) + (size_t)t * NU + uc];

        // ---- layer 1: z(16x64) @ W1(64x128) ----
        V8 za[2];
#pragma unroll
        for (int kc = 0; kc < 2; ++kc) {
            za[kc].v4[0] = *(const bf16x4*)&zbuf[cur][col][kc * 32 + kg * 8];
            za[kc].v4[1] = *(const bf16x4*)&zbuf[cur][col][kc * 32 + kg * 8 + 4];
        }
        f32x4 c1[8];
#pragma unroll
        for (int nt = 0; nt < 8; ++nt) {
            f32x4 acc = { b1v[nt], b1v[nt], b1v[nt], b1v[nt] };
            acc = __builtin_amdgcn_mfma_f32_16x16x32_bf16(za[0].v8, w1f[0][nt], acc, 0, 0, 0);
            acc = __builtin_amdgcn_mfma_f32_16x16x32_bf16(za[1].v8, w1f[1][nt], acc, 0, 0, 0);
            c1[nt] = acc;
        }
#pragma unroll
        for (int nt = 0; nt < 8; ++nt)
#pragma unroll
            for (int r = 0; r < 4; ++r)
                h1s[wrow0 + r][nt * 16 + col] = f2bf(tanh_fast(c1[nt][r]));
        __syncthreads();

        // ---- layer 2: h1(16x128) @ W2(128x128) ----
        V8 ha[4];
#pragma unroll
        for (int kc = 0; kc < 4; ++kc)
            ha[kc].v8 = *(const bf16x8*)&h1s[col][kc * 32 + kg * 8];
        f32x4 c2[8];
#pragma unroll
        for (int nt = 0; nt < 8; ++nt) {
            f32x4 acc = { b2v[nt], b2v[nt], b2v[nt], b2v[nt] };
#pragma unroll
            for (int kc = 0; kc < 4; ++kc)
                acc = __builtin_amdgcn_mfma_f32_16x16x32_bf16(ha[kc].v8, w2f[kc][nt], acc, 0, 0, 0);
            c2[nt] = acc;
        }
#pragma unroll
        for (int nt = 0; nt < 8; ++nt)
#pragma unroll
            for (int r = 0; r < 4; ++r)
                h2s[wrow0 + r][nt * 16 + col] = f2bf(tanh_fast(c2[nt][r]));
        __syncthreads();

        // ---- layer 3: h2(16x128) @ W3(128x8, padded N=16) ----
        V8 h2a[4];
#pragma unroll
        for (int kc = 0; kc < 4; ++kc)
            h2a[kc].v8 = *(const bf16x8*)&h2s[col][kc * 32 + kg * 8];
        f32x4 y = { b3v, b3v, b3v, b3v };
#pragma unroll
        for (int kc = 0; kc < 4; ++kc)
            y = __builtin_amdgcn_mfma_f32_16x16x32_bf16(h2a[kc].v8, w3f[kc], y, 0, 0, 0);

        // ---- store y ----
        if (col < NY) {
#pragma unroll
            for (int r = 0; r < 4; ++r)
                out[(size_t)(b0 + wrow0 + r) * (T_STEPS * NY) + (size_t)t * NY + col] = y[r];
        }

        // ---- z update: z_new = [z[8:40], y, z[44:60], u_t] ----
        const int nxt = cur ^ 1;
        bf16x4 m0 = *(const bf16x4*)&zbuf[cur][urow][8 + 8 * uc];
        bf16x4 m1 = *(const bf16x4*)&zbuf[cur][urow][12 + 8 * uc];
        bf16x4 m2 = *(const bf16x4*)&zbuf[cur][urow][44 + 4 * uc];
        *(bf16x4*)&zbuf[nxt][urow][8 * uc]      = m0;
        *(bf16x4*)&zbuf[nxt][urow][8 * uc + 4]  = m1;
        *(bf16x4*)&zbuf[nxt][urow][40 + 4 * uc] = m2;
        if (col < NY) {
#pragma unroll
            for (int r = 0; r < 4; ++r)
                zbuf[nxt][wrow0 + r][32 + col] = f2bf(y[r]);
        }
        zbuf[nxt][urow][56 + uc] = f2bf(ureg);
        __syncthreads();
        cur = nxt;
    }
}

extern "C" void kernel_launch(void* const* d_in, const int* in_sizes, int n_in,
                              void* d_out, int out_size, void* d_ws, size_t ws_size,
                              hipStream_t stream) {
    (void)in_sizes; (void)n_in; (void)d_ws; (void)ws_size; (void)out_size;
    const float* u  = (const float*)d_in[0];
    const float* z0 = (const float*)d_in[1];
    const float* W1 = (const float*)d_in[2];
    const float* b1 = (const float*)d_in[3];
    const float* W2 = (const float*)d_in[4];
    const float* b2 = (const float*)d_in[5];
    const float* W3 = (const float*)d_in[6];
    const float* b3 = (const float*)d_in[7];
    float* out = (float*)d_out;

    dim3 grid(8192 / 16);   // 512 blocks, one wave each (16 batch rows/wave)
    dim3 block(64);
    cstr_scan_kernel<<<grid, block, 0, stream>>>(u, z0, W1, b1, W2, b2, W3, b3, out);
}

// Round 2
// 1116.130 us; speedup vs baseline: 2.0793x; 2.0793x over previous
//
#include <hip/hip_runtime.h>

#define T_STEPS 1024
#define NZV 60          // valid z width
#define H 128
#define NY 8
#define NU 4
#define ZSTR 72         // padded LDS stride (shorts) for z (144B rows, 16B aligned)
#define HSTR 136        // padded LDS stride (shorts) for h1/h2 (272B rows, 16B aligned)

typedef __attribute__((ext_vector_type(8))) short bf16x8;
typedef __attribute__((ext_vector_type(4))) short bf16x4;
typedef __attribute__((ext_vector_type(4))) float f32x4;

__device__ __forceinline__ unsigned short f2bf(float x) {
    unsigned u = __float_as_uint(x);
    u += 0x7FFFu + ((u >> 16) & 1u);
    return (unsigned short)(u >> 16);
}

// tanh(x) = 1 - 2/(exp(2x)+1); exp2 saturates to inf/0 so no clamp needed.
__device__ __forceinline__ float tanh_fast(float x) {
    float e = __builtin_amdgcn_exp2f(x * 2.8853900817779268f);
    return fmaf(-2.0f, __builtin_amdgcn_rcpf(e + 1.0f), 1.0f);
}

__global__ __launch_bounds__(256, 2)
void cstr_scan_kernel(const float* __restrict__ u_g, const float* __restrict__ z0_g,
                      const float* __restrict__ W1, const float* __restrict__ b1,
                      const float* __restrict__ W2, const float* __restrict__ b2,
                      const float* __restrict__ W3, const float* __restrict__ b3,
                      float* __restrict__ out) {
    __shared__ unsigned short zbuf[2][16][ZSTR];
    __shared__ unsigned short h1s[16][HSTR];
    __shared__ unsigned short h2s[16][HSTR];

    const int tid   = threadIdx.x;
    const int wid   = tid >> 6;          // 0..3
    const int lane  = tid & 63;
    const int b0    = blockIdx.x * 16;   // batch row base
    const int col   = lane & 15;         // MFMA col / A row
    const int kg    = lane >> 4;         // 0..3 (k-group)
    const int wrow0 = kg * 4;            // C-frag row base
    const int urow  = lane >> 2;         // u/z-shift row
    const int uc    = lane & 3;
    const int n0    = wid * 2;           // this wave's first 16-wide n-tile

    // ---- preload weight B-fragments for this wave's 32 hidden cols ----
    bf16x8 w1f[2][2], w2f[4][2], w3f[4];
    float b1v[2], b2v[2], b3v;
#pragma unroll
    for (int nl = 0; nl < 2; ++nl) {
        b1v[nl] = b1[(n0 + nl) * 16 + col];
        b2v[nl] = b2[(n0 + nl) * 16 + col];
    }
    b3v = (col < NY) ? b3[col] : 0.f;

#pragma unroll
    for (int kc = 0; kc < 2; ++kc)
#pragma unroll
        for (int nl = 0; nl < 2; ++nl) {
            bf16x8 v;
#pragma unroll
            for (int j = 0; j < 8; ++j) {
                int k = kc * 32 + kg * 8 + j;
                float w = (k < NZV) ? W1[k * H + (n0 + nl) * 16 + col] : 0.f;
                v[j] = (short)f2bf(w);
            }
            w1f[kc][nl] = v;
        }
#pragma unroll
    for (int kc = 0; kc < 4; ++kc)
#pragma unroll
        for (int nl = 0; nl < 2; ++nl) {
            bf16x8 v;
#pragma unroll
            for (int j = 0; j < 8; ++j) {
                int k = kc * 32 + kg * 8 + j;
                v[j] = (short)f2bf(W2[k * H + (n0 + nl) * 16 + col]);
            }
            w2f[kc][nl] = v;
        }
#pragma unroll
    for (int kc = 0; kc < 4; ++kc) {
        bf16x8 v;
#pragma unroll
        for (int j = 0; j < 8; ++j) {
            int k = kc * 32 + kg * 8 + j;
            float w = (col < NY) ? W3[k * NY + col] : 0.f;
            v[j] = (short)f2bf(w);
        }
        w3f[kc] = v;
    }

    // ---- init z state (bf16) ----
    {
        unsigned short* zs = &zbuf[0][0][0];
        for (int i = tid; i < 2 * 16 * ZSTR; i += 256) zs[i] = 0;
        __syncthreads();
        for (int i = tid; i < 16 * NZV; i += 256) {
            int r = i / NZV, c = i - r * NZV;
            zbuf[0][r][c] = f2bf(z0_g[(size_t)(b0 + r) * NZV + c]);
        }
        __syncthreads();
    }

    float ureg = 0.f, ureg_n = 0.f;
    if (wid == 3)
        ureg = u_g[(size_t)(b0 + urow) * (T_STEPS * NU) + uc];

    f32x4 yprev = { 0.f, 0.f, 0.f, 0.f };

    int cur = 0;
#pragma unroll 1
    for (int t = 0; t < T_STEPS; ++t) {
        const int nxt = cur ^ 1;

        // deferred y-store for step t-1 (overlaps GEMM1; drains at barrier 1)
        if (wid == 0 && t > 0 && col < NY) {
#pragma unroll
            for (int r = 0; r < 4; ++r)
                out[(size_t)(b0 + wrow0 + r) * (T_STEPS * NY) + (size_t)(t - 1) * NY + col] = yprev[r];
        }
        // prefetch u for step t+1 (full step of latency cover)
        if (wid == 3 && t + 1 < T_STEPS)
            ureg_n = u_g[(size_t)(b0 + urow) * (T_STEPS * NU) + (size_t)(t + 1) * NU + uc];

        // ---- phase 1: GEMM1 on this wave's 32 cols ----
        bf16x8 za[2];
#pragma unroll
        for (int kc = 0; kc < 2; ++kc)
            za[kc] = *(const bf16x8*)&zbuf[cur][col][kc * 32 + kg * 8];
        f32x4 c1[2];
#pragma unroll
        for (int nl = 0; nl < 2; ++nl) {
            f32x4 acc = { b1v[nl], b1v[nl], b1v[nl], b1v[nl] };
            acc = __builtin_amdgcn_mfma_f32_16x16x32_bf16(za[0], w1f[0][nl], acc, 0, 0, 0);
            acc = __builtin_amdgcn_mfma_f32_16x16x32_bf16(za[1], w1f[1][nl], acc, 0, 0, 0);
            c1[nl] = acc;
        }
#pragma unroll
        for (int nl = 0; nl < 2; ++nl)
#pragma unroll
            for (int r = 0; r < 4; ++r)
                h1s[wrow0 + r][(n0 + nl) * 16 + col] = f2bf(tanh_fast(c1[nl][r]));

        // wave 3: z shift cur->nxt + u insert (disjoint from y slot, overlaps GEMM1)
        if (wid == 3) {
            bf16x4 m0 = *(const bf16x4*)&zbuf[cur][urow][8 + 8 * uc];
            bf16x4 m1 = *(const bf16x4*)&zbuf[cur][urow][12 + 8 * uc];
            bf16x4 m2 = *(const bf16x4*)&zbuf[cur][urow][44 + 4 * uc];
            *(bf16x4*)&zbuf[nxt][urow][8 * uc]      = m0;
            *(bf16x4*)&zbuf[nxt][urow][8 * uc + 4]  = m1;
            *(bf16x4*)&zbuf[nxt][urow][40 + 4 * uc] = m2;
            zbuf[nxt][urow][56 + uc] = f2bf(ureg);
        }
        __syncthreads();

        // ---- phase 2: GEMM2 on this wave's 32 cols, full K=128 ----
        bf16x8 ha[4];
#pragma unroll
        for (int kc = 0; kc < 4; ++kc)
            ha[kc] = *(const bf16x8*)&h1s[col][kc * 32 + kg * 8];
        f32x4 c2[2];
#pragma unroll
        for (int nl = 0; nl < 2; ++nl) {
            f32x4 a0 = { b2v[nl], b2v[nl], b2v[nl], b2v[nl] };
            f32x4 a1 = { 0.f, 0.f, 0.f, 0.f };
            a0 = __builtin_amdgcn_mfma_f32_16x16x32_bf16(ha[0], w2f[0][nl], a0, 0, 0, 0);
            a1 = __builtin_amdgcn_mfma_f32_16x16x32_bf16(ha[1], w2f[1][nl], a1, 0, 0, 0);
            a0 = __builtin_amdgcn_mfma_f32_16x16x32_bf16(ha[2], w2f[2][nl], a0, 0, 0, 0);
            a1 = __builtin_amdgcn_mfma_f32_16x16x32_bf16(ha[3], w2f[3][nl], a1, 0, 0, 0);
            c2[nl] = a0 + a1;
        }
#pragma unroll
        for (int nl = 0; nl < 2; ++nl)
#pragma unroll
            for (int r = 0; r < 4; ++r)
                h2s[wrow0 + r][(n0 + nl) * 16 + col] = f2bf(tanh_fast(c2[nl][r]));
        __syncthreads();

        // ---- phase 3: wave 0 only — GEMM3 + y insert into z[nxt] ----
        if (wid == 0) {
            bf16x8 h2a[4];
#pragma unroll
            for (int kc = 0; kc < 4; ++kc)
                h2a[kc] = *(const bf16x8*)&h2s[col][kc * 32 + kg * 8];
            f32x4 ya = { b3v, b3v, b3v, b3v };
            f32x4 yb = { 0.f, 0.f, 0.f, 0.f };
            ya = __builtin_amdgcn_mfma_f32_16x16x32_bf16(h2a[0], w3f[0], ya, 0, 0, 0);
            yb = __builtin_amdgcn_mfma_f32_16x16x32_bf16(h2a[1], w3f[1], yb, 0, 0, 0);
            ya = __builtin_amdgcn_mfma_f32_16x16x32_bf16(h2a[2], w3f[2], ya, 0, 0, 0);
            yb = __builtin_amdgcn_mfma_f32_16x16x32_bf16(h2a[3], w3f[3], yb, 0, 0, 0);
            f32x4 y = ya + yb;
            if (col < NY) {
#pragma unroll
                for (int r = 0; r < 4; ++r)
                    zbuf[nxt][wrow0 + r][32 + col] = f2bf(y[r]);
            }
            yprev = y;
        }
        __syncthreads();

        cur = nxt;
        ureg = ureg_n;
    }

    // final y-store (t = T-1)
    if (wid == 0 && (lane & 15) < NY) {
#pragma unroll
        for (int r = 0; r < 4; ++r)
            out[(size_t)(b0 + wrow0 + r) * (T_STEPS * NY) + (size_t)(T_STEPS - 1) * NY + (lane & 15)] = yprev[r];
    }
}

extern "C" void kernel_launch(void* const* d_in, const int* in_sizes, int n_in,
                              void* d_out, int out_size, void* d_ws, size_t ws_size,
                              hipStream_t stream) {
    (void)in_sizes; (void)n_in; (void)d_ws; (void)ws_size; (void)out_size;
    const float* u  = (const float*)d_in[0];
    const float* z0 = (const float*)d_in[1];
    const float* W1 = (const float*)d_in[2];
    const float* b1 = (const float*)d_in[3];
    const float* W2 = (const float*)d_in[4];
    const float* b2 = (const float*)d_in[5];
    const float* W3 = (const float*)d_in[6];
    const float* b3 = (const float*)d_in[7];
    float* out = (float*)d_out;

    dim3 grid(8192 / 16);   // 512 blocks x 4 waves; 16 batch rows/block
    dim3 block(256);
    cstr_scan_kernel<<<grid, block, 0, stream>>>(u, z0, W1, b1, W2, b2, W3, b3, out);
}